// Round 9
// baseline (753.738 us; speedup 1.0000x reference)
//
#include <hip/hip_runtime.h>

#define N_USERS 200000
#define N_ITEMS 50000
#define NTOT    (N_USERS + N_ITEMS)    // 250000
#define DIM     64
#define BATCH   4096

#define RB      256                    // rows per bucket
#define NB      ((NTOT + RB - 1) / RB) // 977 buckets
#define TILE    8192                   // edges per phase-A tile
#define CAP     15360                  // LDS-sortable entries/bucket (item buckets mean 10.2K, ~50 sd head)

// ---------------- build: coarse bucket histogram ----------------
__global__ void coarse_hist(const int* __restrict__ rows, int* __restrict__ bCnt, int nE) {
    __shared__ int h[NB];
    for (int b = threadIdx.x; b < NB; b += blockDim.x) h[b] = 0;
    __syncthreads();
    const int t  = blockIdx.x * blockDim.x + threadIdx.x;
    const int nT = gridDim.x * blockDim.x;
    const int n4 = nE >> 2;
    for (int i = t; i < n4; i += nT) {
        const int4 r4 = reinterpret_cast<const int4*>(rows)[i];
        atomicAdd(&h[r4.x >> 8], 1);
        atomicAdd(&h[r4.y >> 8], 1);
        atomicAdd(&h[r4.z >> 8], 1);
        atomicAdd(&h[r4.w >> 8], 1);
    }
    for (int e = (n4 << 2) + t; e < nE; e += nT) atomicAdd(&h[rows[e] >> 8], 1);
    __syncthreads();
    for (int b = threadIdx.x; b < NB; b += blockDim.x) {
        const int c = h[b];
        if (c) atomicAdd(&bCnt[b], c);
    }
}

// single-block scan of NB bucket counts -> bStart (exclusive, +total at [NB]), bCur copy
__global__ void bucket_scan(const int* __restrict__ bCnt, int* __restrict__ bStart,
                            int* __restrict__ bCur) {
    __shared__ int sc[1024];
    const int t = threadIdx.x;
    const int v = (t < NB) ? bCnt[t] : 0;
    sc[t] = v;
    __syncthreads();
    int incl = v;
    for (int s = 1; s < 1024; s <<= 1) {
        const int add = (t >= s) ? sc[t - s] : 0;
        __syncthreads();
        incl += add;
        sc[t] = incl;
        __syncthreads();
    }
    if (t < NB) {
        const int excl = incl - v;
        bStart[t] = excl;
        bCur[t]   = excl;
        if (t == NB - 1) bStart[NB] = incl;
    }
}

// ---------------- build: phase A — LDS-ranked multisplit into buckets ----------------
// entry = col(18b) | rowlow(8b)<<18 ; writes land in short runs per (tile,bucket)
__global__ __launch_bounds__(256) void phase_a(const int* __restrict__ rows,
                                               const int* __restrict__ cols,
                                               int* __restrict__ bCur,
                                               int* __restrict__ entA, int nE) {
    __shared__ int cnt[NB];
    __shared__ int base[NB];
    const int tid = threadIdx.x;
    for (int b = tid; b < NB; b += 256) cnt[b] = 0;
    __syncthreads();
    const int tb = blockIdx.x * TILE;
    const int te = min(tb + TILE, nE);
    const int nv = (te - tb) >> 2;                 // int4 groups in this tile
    const int4* rows4 = reinterpret_cast<const int4*>(rows + tb);
    const int4* cols4 = reinterpret_cast<const int4*>(cols + tb);
    for (int i = tid; i < nv; i += 256) {
        const int4 r4 = rows4[i];
        atomicAdd(&cnt[r4.x >> 8], 1);
        atomicAdd(&cnt[r4.y >> 8], 1);
        atomicAdd(&cnt[r4.z >> 8], 1);
        atomicAdd(&cnt[r4.w >> 8], 1);
    }
    for (int e = tb + (nv << 2) + tid; e < te; e += 256) atomicAdd(&cnt[rows[e] >> 8], 1);
    __syncthreads();
    for (int b = tid; b < NB; b += 256) {
        const int c = cnt[b];
        if (c) base[b] = atomicAdd(&bCur[b], c);
        cnt[b] = 0;
    }
    __syncthreads();
    for (int i = tid; i < nv; i += 256) {
        const int4 r4 = rows4[i];
        const int4 c4 = cols4[i];
        int r, b, rank;
        r = r4.x; b = r >> 8; rank = atomicAdd(&cnt[b], 1);
        entA[base[b] + rank] = c4.x | ((r & (RB - 1)) << 18);
        r = r4.y; b = r >> 8; rank = atomicAdd(&cnt[b], 1);
        entA[base[b] + rank] = c4.y | ((r & (RB - 1)) << 18);
        r = r4.z; b = r >> 8; rank = atomicAdd(&cnt[b], 1);
        entA[base[b] + rank] = c4.z | ((r & (RB - 1)) << 18);
        r = r4.w; b = r >> 8; rank = atomicAdd(&cnt[b], 1);
        entA[base[b] + rank] = c4.w | ((r & (RB - 1)) << 18);
    }
    for (int e = tb + (nv << 2) + tid; e < te; e += 256) {
        const int r = rows[e];
        const int b = r >> 8;
        const int rank = atomicAdd(&cnt[b], 1);
        entA[base[b] + rank] = cols[e] | ((r & (RB - 1)) << 18);
    }
}

// ---------------- build: phase B — in-LDS row sort per bucket + per-row column sort
//                   + P + dis ----------------
__global__ __launch_bounds__(256) void phase_b(const int* __restrict__ entA,
                                               const int* __restrict__ bStart,
                                               int* __restrict__ ccol,
                                               int* __restrict__ P,
                                               float* __restrict__ dis) {
    __shared__ int cnt2[RB];
    __shared__ int sc[RB];
    __shared__ int cur[RB];
    __shared__ int srt[CAP];
    const int b   = blockIdx.x;
    const int tid = threadIdx.x;   // blockDim == RB == 256
    const int beg = bStart[b], end = bStart[b + 1];
    const int n   = end - beg;
    cnt2[tid] = 0;
    __syncthreads();
    for (int i = tid; i < n; i += 256) atomicAdd(&cnt2[entA[beg + i] >> 18], 1);
    __syncthreads();
    const int v = cnt2[tid];
    sc[tid] = v;
    __syncthreads();
    int incl = v;
    for (int s = 1; s < 256; s <<= 1) {
        const int add = (tid >= s) ? sc[tid - s] : 0;
        __syncthreads();
        incl += add;
        sc[tid] = incl;
        __syncthreads();
    }
    const int myBeg = incl - v;             // this row's segment start within bucket
    cur[tid] = myBeg;
    const int row = b * RB + tid;
    if (row < NTOT) {
        P[row]   = beg + incl;              // end offset of row (start = P[row-1])
        dis[row] = 1.0f / sqrtf((float)v + 1e-9f);
    }
    __syncthreads();
    if (n <= CAP) {
        for (int i = tid; i < n; i += 256) {
            const int e = entA[beg + i];
            const int pos = atomicAdd(&cur[e >> 18], 1);
            srt[pos] = e & 0x3FFFF;
        }
        __syncthreads();
        // per-row insertion sort by column: sorted gathers walk x in address
        // order -> banded access across concurrent waves -> L2 locality
        for (int i = 1; i < v; ++i) {
            const int key = srt[myBeg + i];
            int j = i - 1;
            while (j >= 0 && srt[myBeg + j] > key) {
                srt[myBeg + j + 1] = srt[myBeg + j];
                --j;
            }
            srt[myBeg + j + 1] = key;
        }
        __syncthreads();
        for (int i = tid; i < n; i += 256) ccol[beg + i] = srt[i];
    } else {                                // statistical never; correctness backstop
        for (int i = tid; i < n; i += 256) {
            const int e = entA[beg + i];
            const int pos = atomicAdd(&cur[e >> 18], 1);
            ccol[beg + pos] = e & 0x3FFFF;
        }
    }
}

// ---------------- SpMM: one wave per row, 4 edges/wave via float4 lanes ----------------
// lane = (grp = lane>>4 -> edge group, sub = lane&15 -> dim quarter).
// Each lane loads float4 (16B): one VMEM instr covers 4 edges (1KB).
// Epilogue: xor-shuffle reduce across groups, lanes 0-15 write float4.
__global__ __launch_bounds__(256) void spmm_csr(const float* __restrict__ x,
                                                const int* __restrict__ P,
                                                const int* __restrict__ ccol,
                                                const float* __restrict__ dis,
                                                float* __restrict__ y) {
    const int lane = threadIdx.x & 63;
    const int sub  = lane & 15;
    const int grp  = lane >> 4;
    const int wid  = blockIdx.x * 4 + (threadIdx.x >> 6);
    if (wid >= NTOT) return;
    const int beg = (wid == 0) ? 0 : P[wid - 1];
    const int end = P[wid];
    const float4* x4 = reinterpret_cast<const float4*>(x);
    float4 acc = make_float4(0.f, 0.f, 0.f, 0.f);
    int e = beg + grp;
    for (; e + 12 < end; e += 16) {         // 4 gathers in flight per lane
        const int c0 = ccol[e], c1 = ccol[e + 4], c2 = ccol[e + 8], c3 = ccol[e + 12];
        const float w0 = dis[c0], w1 = dis[c1], w2 = dis[c2], w3 = dis[c3];
        const float4 v0 = x4[(size_t)c0 * 16 + sub];
        const float4 v1 = x4[(size_t)c1 * 16 + sub];
        const float4 v2 = x4[(size_t)c2 * 16 + sub];
        const float4 v3 = x4[(size_t)c3 * 16 + sub];
        acc.x += w0 * v0.x + w1 * v1.x + w2 * v2.x + w3 * v3.x;
        acc.y += w0 * v0.y + w1 * v1.y + w2 * v2.y + w3 * v3.y;
        acc.z += w0 * v0.z + w1 * v1.z + w2 * v2.z + w3 * v3.z;
        acc.w += w0 * v0.w + w1 * v1.w + w2 * v2.w + w3 * v3.w;
    }
    for (; e < end; e += 4) {
        const int c = ccol[e];
        const float w = dis[c];
        const float4 v = x4[(size_t)c * 16 + sub];
        acc.x += w * v.x; acc.y += w * v.y; acc.z += w * v.z; acc.w += w * v.w;
    }
    // reduce across the 4 edge groups (lanes xor 16, xor 32)
    acc.x += __shfl_xor(acc.x, 16); acc.y += __shfl_xor(acc.y, 16);
    acc.z += __shfl_xor(acc.z, 16); acc.w += __shfl_xor(acc.w, 16);
    acc.x += __shfl_xor(acc.x, 32); acc.y += __shfl_xor(acc.y, 32);
    acc.z += __shfl_xor(acc.z, 32); acc.w += __shfl_xor(acc.w, 32);
    if (grp == 0) {
        const float dr = dis[wid];
        acc.x *= dr; acc.y *= dr; acc.z *= dr; acc.w *= dr;
        reinterpret_cast<float4*>(y)[(size_t)wid * 16 + sub] = acc;
    }
}

// layer-3: only the 12,288 sampled rows, fused with final accumulate + /4
__global__ __launch_bounds__(256) void spmm_rows_out(const float* __restrict__ x,
                                                     const int* __restrict__ P,
                                                     const int* __restrict__ ccol,
                                                     const float* __restrict__ dis,
                                                     const int* __restrict__ users,
                                                     const int* __restrict__ pos,
                                                     const int* __restrict__ neg,
                                                     float* __restrict__ out) {
    const int lane = threadIdx.x & 63;
    const int sub  = lane & 15;
    const int grp  = lane >> 4;
    const int wid  = blockIdx.x * 4 + (threadIdx.x >> 6);
    if (wid >= 3 * BATCH) return;
    const int s = wid / BATCH;
    const int j = wid - s * BATCH;
    const int row = (s == 0) ? users[j] : (s == 1) ? pos[j] + N_USERS : neg[j] + N_USERS;
    const int beg = (row == 0) ? 0 : P[row - 1];
    const int end = P[row];
    const float4* x4 = reinterpret_cast<const float4*>(x);
    float4 acc = make_float4(0.f, 0.f, 0.f, 0.f);
    int e = beg + grp;
    for (; e + 12 < end; e += 16) {
        const int c0 = ccol[e], c1 = ccol[e + 4], c2 = ccol[e + 8], c3 = ccol[e + 12];
        const float w0 = dis[c0], w1 = dis[c1], w2 = dis[c2], w3 = dis[c3];
        const float4 v0 = x4[(size_t)c0 * 16 + sub];
        const float4 v1 = x4[(size_t)c1 * 16 + sub];
        const float4 v2 = x4[(size_t)c2 * 16 + sub];
        const float4 v3 = x4[(size_t)c3 * 16 + sub];
        acc.x += w0 * v0.x + w1 * v1.x + w2 * v2.x + w3 * v3.x;
        acc.y += w0 * v0.y + w1 * v1.y + w2 * v2.y + w3 * v3.y;
        acc.z += w0 * v0.z + w1 * v1.z + w2 * v2.z + w3 * v3.z;
        acc.w += w0 * v0.w + w1 * v1.w + w2 * v2.w + w3 * v3.w;
    }
    for (; e < end; e += 4) {
        const int c = ccol[e];
        const float w = dis[c];
        const float4 v = x4[(size_t)c * 16 + sub];
        acc.x += w * v.x; acc.y += w * v.y; acc.z += w * v.z; acc.w += w * v.w;
    }
    acc.x += __shfl_xor(acc.x, 16); acc.y += __shfl_xor(acc.y, 16);
    acc.z += __shfl_xor(acc.z, 16); acc.w += __shfl_xor(acc.w, 16);
    acc.x += __shfl_xor(acc.x, 32); acc.y += __shfl_xor(acc.y, 32);
    acc.z += __shfl_xor(acc.z, 32); acc.w += __shfl_xor(acc.w, 32);
    if (grp == 0) {
        const float dr = dis[row];
        float4* out4 = reinterpret_cast<float4*>(out);
        const size_t o = (size_t)(s * BATCH + j) * 16 + sub;
        float4 ov = out4[o];
        ov.x = (ov.x + acc.x * dr) * 0.25f;
        ov.y = (ov.y + acc.y * dr) * 0.25f;
        ov.z = (ov.z + acc.z * dr) * 0.25f;
        ov.w = (ov.w + acc.w * dr) * 0.25f;
        out4[o] = ov;
    }
}

// ---------------- atomic-scatter fallback (small-ws safety) ----------------
__global__ void spmm_scatter(const float* __restrict__ x, const int* __restrict__ rows,
                             const int* __restrict__ cols, const float* __restrict__ vals,
                             float* __restrict__ y, int nE) {
    const int lane = threadIdx.x & 63;
    const int wid  = blockIdx.x * (blockDim.x >> 6) + (threadIdx.x >> 6);
    const int nw   = gridDim.x * (blockDim.x >> 6);
    for (int e = wid; e < nE; e += nw)
        atomicAdd(&y[(size_t)rows[e] * DIM + lane], vals[e] * x[(size_t)cols[e] * DIM + lane]);
}

// ---------------- output assembly ----------------
__global__ void init_out(const float* __restrict__ emb, const int* __restrict__ users,
                         const int* __restrict__ pos, const int* __restrict__ neg,
                         float* __restrict__ out) {
    const int t = blockIdx.x * blockDim.x + threadIdx.x;
    const int lane = t & 63;
    const int w = t >> 6;
    if (w >= 3 * BATCH) return;
    const int s = w / BATCH;
    const int j = w - s * BATCH;
    const int row = (s == 0) ? users[j] : (s == 1) ? pos[j] + N_USERS : neg[j] + N_USERS;
    const float v = emb[(size_t)row * DIM + lane];
    out[(size_t)(s * BATCH + j) * DIM + lane] = v;        // final_* accumulator (layer 0)
    out[(size_t)((s + 3) * BATCH + j) * DIM + lane] = v;  // init_* output
}

__global__ void gather_addscale(const float* __restrict__ e, const int* __restrict__ users,
                                const int* __restrict__ pos, const int* __restrict__ neg,
                                float* __restrict__ out, float scale) {
    const int t = blockIdx.x * blockDim.x + threadIdx.x;
    const int lane = t & 63;
    const int w = t >> 6;
    if (w >= 3 * BATCH) return;
    const int s = w / BATCH;
    const int j = w - s * BATCH;
    const int row = (s == 0) ? users[j] : (s == 1) ? pos[j] + N_USERS : neg[j] + N_USERS;
    const size_t o = (size_t)(s * BATCH + j) * DIM + lane;
    out[o] = (out[o] + e[(size_t)row * DIM + lane]) * scale;
}

// ---------------- host ----------------
extern "C" void kernel_launch(void* const* d_in, const int* in_sizes, int n_in,
                              void* d_out, int out_size, void* d_ws, size_t ws_size,
                              hipStream_t stream) {
    const float* emb  = (const float*)d_in[0];
    const int*   rows = (const int*)d_in[1];
    const int*   cols = (const int*)d_in[2];
    const float* vals = (const float*)d_in[3];
    const int*   users = (const int*)d_in[4];
    const int*   pos   = (const int*)d_in[5];
    const int*   neg   = (const int*)d_in[6];
    float* out = (float*)d_out;

    const int nE = in_sizes[1];
    auto rup = [](size_t x) { return (x + 255) & ~(size_t)255; };
    const size_t szBuf = rup((size_t)NTOT * DIM * sizeof(float));   // 64 MB
    const size_t szCol = rup((size_t)nE * sizeof(int));             // 16 MB
    const size_t szP   = rup((size_t)NTOT * sizeof(int));           // 1 MB
    const size_t szDis = rup((size_t)NTOT * sizeof(float));         // 1 MB
    const size_t szBk  = rup((size_t)(NB + 1) * sizeof(int));

    char* w = (char*)d_ws;
    float* bufA = (float*)w; w += szBuf;
    float* bufB = (float*)w; w += szBuf;
    int* entA   = (int*)bufB;              // phase-A entries alias bufB (dead before spmm-2)
    int*   ccol = (int*)w;   w += szCol;
    int*   P    = (int*)w;   w += szP;
    float* dis  = (float*)w; w += szDis;
    int* bCnt   = (int*)w;   w += szBk;
    int* bStart = (int*)w;   w += szBk;
    int* bCur   = (int*)w;   w += szBk;
    const size_t need = (size_t)((char*)w - (char*)d_ws);

    const int gatherBlocks = (3 * BATCH * DIM + 255) / 256;

    init_out<<<gatherBlocks, 256, 0, stream>>>(emb, users, pos, neg, out);

    if (ws_size >= need && nE > 0) {
        // ---- build bucketed CSR (coalesced two-phase counting sort, col-sorted rows) ----
        hipMemsetAsync(bCnt, 0, (size_t)NB * sizeof(int), stream);
        coarse_hist<<<512, 256, 0, stream>>>(rows, bCnt, nE);
        bucket_scan<<<1, 1024, 0, stream>>>(bCnt, bStart, bCur);
        const int nTiles = (nE + TILE - 1) / TILE;
        phase_a<<<nTiles, 256, 0, stream>>>(rows, cols, bCur, entA, nE);
        phase_b<<<NB, 256, 0, stream>>>(entA, bStart, ccol, P, dis);

        const int spmmBlocks = (NTOT + 3) / 4;
        // layers 1,2: full SpMM
        spmm_csr<<<spmmBlocks, 256, 0, stream>>>(emb,  P, ccol, dis, bufA);
        gather_addscale<<<gatherBlocks, 256, 0, stream>>>(bufA, users, pos, neg, out, 1.0f);
        spmm_csr<<<spmmBlocks, 256, 0, stream>>>(bufA, P, ccol, dis, bufB);
        gather_addscale<<<gatherBlocks, 256, 0, stream>>>(bufB, users, pos, neg, out, 1.0f);
        // layer 3: only sampled rows, fused accumulate + /4
        const int rowsBlocks = (3 * BATCH + 3) / 4;
        spmm_rows_out<<<rowsBlocks, 256, 0, stream>>>(bufB, P, ccol, dis, users, pos, neg, out);
    } else {
        // ---- atomic fallback ----
        const size_t bufBytes = (size_t)NTOT * DIM * sizeof(float);
        hipMemsetAsync(bufA, 0, bufBytes, stream);
        spmm_scatter<<<2048, 256, 0, stream>>>(emb, rows, cols, vals, bufA, nE);
        gather_addscale<<<gatherBlocks, 256, 0, stream>>>(bufA, users, pos, neg, out, 1.0f);
        hipMemsetAsync(bufB, 0, bufBytes, stream);
        spmm_scatter<<<2048, 256, 0, stream>>>(bufA, rows, cols, vals, bufB, nE);
        gather_addscale<<<gatherBlocks, 256, 0, stream>>>(bufB, users, pos, neg, out, 1.0f);
        hipMemsetAsync(bufA, 0, bufBytes, stream);
        spmm_scatter<<<2048, 256, 0, stream>>>(bufB, rows, cols, vals, bufA, nE);
        gather_addscale<<<gatherBlocks, 256, 0, stream>>>(bufA, users, pos, neg, out, 0.25f);
    }
}

// Round 12
// 572.456 us; speedup vs baseline: 1.3167x; 1.3167x over previous
//
#include <hip/hip_runtime.h>

#define N_USERS 200000
#define N_ITEMS 50000
#define NTOT    (N_USERS + N_ITEMS)    // 250000
#define DIM     64
#define BATCH   4096

#define RB      256                    // rows per bucket
#define NB      ((NTOT + RB - 1) / RB) // 977 buckets
#define TILE    8192                   // edges per phase-A tile
#define CAP     15360                  // LDS-sortable entries/bucket (item buckets mean 10.2K, ~50 sd head)

// ---------------- build: coarse bucket histogram ----------------
__global__ void coarse_hist(const int* __restrict__ rows, int* __restrict__ bCnt, int nE) {
    __shared__ int h[NB];
    for (int b = threadIdx.x; b < NB; b += blockDim.x) h[b] = 0;
    __syncthreads();
    const int t  = blockIdx.x * blockDim.x + threadIdx.x;
    const int nT = gridDim.x * blockDim.x;
    const int n4 = nE >> 2;
    for (int i = t; i < n4; i += nT) {
        const int4 r4 = reinterpret_cast<const int4*>(rows)[i];
        atomicAdd(&h[r4.x >> 8], 1);
        atomicAdd(&h[r4.y >> 8], 1);
        atomicAdd(&h[r4.z >> 8], 1);
        atomicAdd(&h[r4.w >> 8], 1);
    }
    for (int e = (n4 << 2) + t; e < nE; e += nT) atomicAdd(&h[rows[e] >> 8], 1);
    __syncthreads();
    for (int b = threadIdx.x; b < NB; b += blockDim.x) {
        const int c = h[b];
        if (c) atomicAdd(&bCnt[b], c);
    }
}

// single-block scan of NB bucket counts -> bStart (exclusive, +total at [NB]), bCur copy
__global__ void bucket_scan(const int* __restrict__ bCnt, int* __restrict__ bStart,
                            int* __restrict__ bCur) {
    __shared__ int sc[1024];
    const int t = threadIdx.x;
    const int v = (t < NB) ? bCnt[t] : 0;
    sc[t] = v;
    __syncthreads();
    int incl = v;
    for (int s = 1; s < 1024; s <<= 1) {
        const int add = (t >= s) ? sc[t - s] : 0;
        __syncthreads();
        incl += add;
        sc[t] = incl;
        __syncthreads();
    }
    if (t < NB) {
        const int excl = incl - v;
        bStart[t] = excl;
        bCur[t]   = excl;
        if (t == NB - 1) bStart[NB] = incl;
    }
}

// ---------------- build: phase A — LDS-ranked multisplit into buckets ----------------
// entry = col(18b) | rowlow(8b)<<18 ; writes land in short runs per (tile,bucket)
__global__ __launch_bounds__(256) void phase_a(const int* __restrict__ rows,
                                               const int* __restrict__ cols,
                                               int* __restrict__ bCur,
                                               int* __restrict__ entA, int nE) {
    __shared__ int cnt[NB];
    __shared__ int base[NB];
    const int tid = threadIdx.x;
    for (int b = tid; b < NB; b += 256) cnt[b] = 0;
    __syncthreads();
    const int tb = blockIdx.x * TILE;
    const int te = min(tb + TILE, nE);
    const int nv = (te - tb) >> 2;                 // int4 groups in this tile
    const int4* rows4 = reinterpret_cast<const int4*>(rows + tb);
    const int4* cols4 = reinterpret_cast<const int4*>(cols + tb);
    for (int i = tid; i < nv; i += 256) {
        const int4 r4 = rows4[i];
        atomicAdd(&cnt[r4.x >> 8], 1);
        atomicAdd(&cnt[r4.y >> 8], 1);
        atomicAdd(&cnt[r4.z >> 8], 1);
        atomicAdd(&cnt[r4.w >> 8], 1);
    }
    for (int e = tb + (nv << 2) + tid; e < te; e += 256) atomicAdd(&cnt[rows[e] >> 8], 1);
    __syncthreads();
    for (int b = tid; b < NB; b += 256) {
        const int c = cnt[b];
        if (c) base[b] = atomicAdd(&bCur[b], c);
        cnt[b] = 0;
    }
    __syncthreads();
    for (int i = tid; i < nv; i += 256) {
        const int4 r4 = rows4[i];
        const int4 c4 = cols4[i];
        int r, b, rank;
        r = r4.x; b = r >> 8; rank = atomicAdd(&cnt[b], 1);
        entA[base[b] + rank] = c4.x | ((r & (RB - 1)) << 18);
        r = r4.y; b = r >> 8; rank = atomicAdd(&cnt[b], 1);
        entA[base[b] + rank] = c4.y | ((r & (RB - 1)) << 18);
        r = r4.z; b = r >> 8; rank = atomicAdd(&cnt[b], 1);
        entA[base[b] + rank] = c4.z | ((r & (RB - 1)) << 18);
        r = r4.w; b = r >> 8; rank = atomicAdd(&cnt[b], 1);
        entA[base[b] + rank] = c4.w | ((r & (RB - 1)) << 18);
    }
    for (int e = tb + (nv << 2) + tid; e < te; e += 256) {
        const int r = rows[e];
        const int b = r >> 8;
        const int rank = atomicAdd(&cnt[b], 1);
        entA[base[b] + rank] = cols[e] | ((r & (RB - 1)) << 18);
    }
}

// ---------------- build: phase B — in-LDS row sort per bucket + P + dis ----------------
// (round-5 fast version: no per-row column sort — the serial insertion sort cost
//  224 µs with 5.5M LDS bank conflicts in round 9)
__global__ __launch_bounds__(256) void phase_b(const int* __restrict__ entA,
                                               const int* __restrict__ bStart,
                                               int* __restrict__ ccol,
                                               int* __restrict__ P,
                                               float* __restrict__ dis) {
    __shared__ int cnt2[RB];
    __shared__ int sc[RB];
    __shared__ int cur[RB];
    __shared__ int srt[CAP];
    const int b   = blockIdx.x;
    const int tid = threadIdx.x;   // blockDim == RB == 256
    const int beg = bStart[b], end = bStart[b + 1];
    const int n   = end - beg;
    cnt2[tid] = 0;
    __syncthreads();
    for (int i = tid; i < n; i += 256) atomicAdd(&cnt2[entA[beg + i] >> 18], 1);
    __syncthreads();
    const int v = cnt2[tid];
    sc[tid] = v;
    __syncthreads();
    int incl = v;
    for (int s = 1; s < 256; s <<= 1) {
        const int add = (tid >= s) ? sc[tid - s] : 0;
        __syncthreads();
        incl += add;
        sc[tid] = incl;
        __syncthreads();
    }
    cur[tid] = incl - v;                    // exclusive offset within bucket
    const int row = b * RB + tid;
    if (row < NTOT) {
        P[row]   = beg + incl;              // end offset of row (start = P[row-1])
        dis[row] = 1.0f / sqrtf((float)v + 1e-9f);
    }
    __syncthreads();
    if (n <= CAP) {
        for (int i = tid; i < n; i += 256) {
            const int e = entA[beg + i];
            const int pos = atomicAdd(&cur[e >> 18], 1);
            srt[pos] = e & 0x3FFFF;
        }
        __syncthreads();
        for (int i = tid; i < n; i += 256) ccol[beg + i] = srt[i];
    } else {                                // statistical never; correctness backstop
        for (int i = tid; i < n; i += 256) {
            const int e = entA[beg + i];
            const int pos = atomicAdd(&cur[e >> 18], 1);
            ccol[beg + pos] = e & 0x3FFFF;
        }
    }
}

// ---------------- SpMM: one wave per row, 4 edges/wave via float4 lanes ----------------
// lane = (grp = lane>>4 -> edge group, sub = lane&15 -> dim quarter).
// Each lane loads float4 (16B): one VMEM instr covers 4 edges (1KB).
// Epilogue: xor-shuffle reduce across groups, lanes 0-15 write float4.
__global__ __launch_bounds__(256) void spmm_csr(const float* __restrict__ x,
                                                const int* __restrict__ P,
                                                const int* __restrict__ ccol,
                                                const float* __restrict__ dis,
                                                float* __restrict__ y) {
    const int lane = threadIdx.x & 63;
    const int sub  = lane & 15;
    const int grp  = lane >> 4;
    const int wid  = blockIdx.x * 4 + (threadIdx.x >> 6);
    if (wid >= NTOT) return;
    const int beg = (wid == 0) ? 0 : P[wid - 1];
    const int end = P[wid];
    const float4* x4 = reinterpret_cast<const float4*>(x);
    float4 acc = make_float4(0.f, 0.f, 0.f, 0.f);
    int e = beg + grp;
    for (; e + 12 < end; e += 16) {         // 4 gathers in flight per lane
        const int c0 = ccol[e], c1 = ccol[e + 4], c2 = ccol[e + 8], c3 = ccol[e + 12];
        const float w0 = dis[c0], w1 = dis[c1], w2 = dis[c2], w3 = dis[c3];
        const float4 v0 = x4[(size_t)c0 * 16 + sub];
        const float4 v1 = x4[(size_t)c1 * 16 + sub];
        const float4 v2 = x4[(size_t)c2 * 16 + sub];
        const float4 v3 = x4[(size_t)c3 * 16 + sub];
        acc.x += w0 * v0.x + w1 * v1.x + w2 * v2.x + w3 * v3.x;
        acc.y += w0 * v0.y + w1 * v1.y + w2 * v2.y + w3 * v3.y;
        acc.z += w0 * v0.z + w1 * v1.z + w2 * v2.z + w3 * v3.z;
        acc.w += w0 * v0.w + w1 * v1.w + w2 * v2.w + w3 * v3.w;
    }
    for (; e < end; e += 4) {
        const int c = ccol[e];
        const float w = dis[c];
        const float4 v = x4[(size_t)c * 16 + sub];
        acc.x += w * v.x; acc.y += w * v.y; acc.z += w * v.z; acc.w += w * v.w;
    }
    // reduce across the 4 edge groups (lanes xor 16, xor 32)
    acc.x += __shfl_xor(acc.x, 16); acc.y += __shfl_xor(acc.y, 16);
    acc.z += __shfl_xor(acc.z, 16); acc.w += __shfl_xor(acc.w, 16);
    acc.x += __shfl_xor(acc.x, 32); acc.y += __shfl_xor(acc.y, 32);
    acc.z += __shfl_xor(acc.z, 32); acc.w += __shfl_xor(acc.w, 32);
    if (grp == 0) {
        const float dr = dis[wid];
        acc.x *= dr; acc.y *= dr; acc.z *= dr; acc.w *= dr;
        reinterpret_cast<float4*>(y)[(size_t)wid * 16 + sub] = acc;
    }
}

// layer-3: only the 12,288 sampled rows, fused with final accumulate + /4
__global__ __launch_bounds__(256) void spmm_rows_out(const float* __restrict__ x,
                                                     const int* __restrict__ P,
                                                     const int* __restrict__ ccol,
                                                     const float* __restrict__ dis,
                                                     const int* __restrict__ users,
                                                     const int* __restrict__ pos,
                                                     const int* __restrict__ neg,
                                                     float* __restrict__ out) {
    const int lane = threadIdx.x & 63;
    const int sub  = lane & 15;
    const int grp  = lane >> 4;
    const int wid  = blockIdx.x * 4 + (threadIdx.x >> 6);
    if (wid >= 3 * BATCH) return;
    const int s = wid / BATCH;
    const int j = wid - s * BATCH;
    const int row = (s == 0) ? users[j] : (s == 1) ? pos[j] + N_USERS : neg[j] + N_USERS;
    const int beg = (row == 0) ? 0 : P[row - 1];
    const int end = P[row];
    const float4* x4 = reinterpret_cast<const float4*>(x);
    float4 acc = make_float4(0.f, 0.f, 0.f, 0.f);
    int e = beg + grp;
    for (; e + 12 < end; e += 16) {
        const int c0 = ccol[e], c1 = ccol[e + 4], c2 = ccol[e + 8], c3 = ccol[e + 12];
        const float w0 = dis[c0], w1 = dis[c1], w2 = dis[c2], w3 = dis[c3];
        const float4 v0 = x4[(size_t)c0 * 16 + sub];
        const float4 v1 = x4[(size_t)c1 * 16 + sub];
        const float4 v2 = x4[(size_t)c2 * 16 + sub];
        const float4 v3 = x4[(size_t)c3 * 16 + sub];
        acc.x += w0 * v0.x + w1 * v1.x + w2 * v2.x + w3 * v3.x;
        acc.y += w0 * v0.y + w1 * v1.y + w2 * v2.y + w3 * v3.y;
        acc.z += w0 * v0.z + w1 * v1.z + w2 * v2.z + w3 * v3.z;
        acc.w += w0 * v0.w + w1 * v1.w + w2 * v2.w + w3 * v3.w;
    }
    for (; e < end; e += 4) {
        const int c = ccol[e];
        const float w = dis[c];
        const float4 v = x4[(size_t)c * 16 + sub];
        acc.x += w * v.x; acc.y += w * v.y; acc.z += w * v.z; acc.w += w * v.w;
    }
    acc.x += __shfl_xor(acc.x, 16); acc.y += __shfl_xor(acc.y, 16);
    acc.z += __shfl_xor(acc.z, 16); acc.w += __shfl_xor(acc.w, 16);
    acc.x += __shfl_xor(acc.x, 32); acc.y += __shfl_xor(acc.y, 32);
    acc.z += __shfl_xor(acc.z, 32); acc.w += __shfl_xor(acc.w, 32);
    if (grp == 0) {
        const float dr = dis[row];
        float4* out4 = reinterpret_cast<float4*>(out);
        const size_t o = (size_t)(s * BATCH + j) * 16 + sub;
        float4 ov = out4[o];
        ov.x = (ov.x + acc.x * dr) * 0.25f;
        ov.y = (ov.y + acc.y * dr) * 0.25f;
        ov.z = (ov.z + acc.z * dr) * 0.25f;
        ov.w = (ov.w + acc.w * dr) * 0.25f;
        out4[o] = ov;
    }
}

// ---------------- atomic-scatter fallback (small-ws safety) ----------------
__global__ void spmm_scatter(const float* __restrict__ x, const int* __restrict__ rows,
                             const int* __restrict__ cols, const float* __restrict__ vals,
                             float* __restrict__ y, int nE) {
    const int lane = threadIdx.x & 63;
    const int wid  = blockIdx.x * (blockDim.x >> 6) + (threadIdx.x >> 6);
    const int nw   = gridDim.x * (blockDim.x >> 6);
    for (int e = wid; e < nE; e += nw)
        atomicAdd(&y[(size_t)rows[e] * DIM + lane], vals[e] * x[(size_t)cols[e] * DIM + lane]);
}

// ---------------- output assembly ----------------
__global__ void init_out(const float* __restrict__ emb, const int* __restrict__ users,
                         const int* __restrict__ pos, const int* __restrict__ neg,
                         float* __restrict__ out) {
    const int t = blockIdx.x * blockDim.x + threadIdx.x;
    const int lane = t & 63;
    const int w = t >> 6;
    if (w >= 3 * BATCH) return;
    const int s = w / BATCH;
    const int j = w - s * BATCH;
    const int row = (s == 0) ? users[j] : (s == 1) ? pos[j] + N_USERS : neg[j] + N_USERS;
    const float v = emb[(size_t)row * DIM + lane];
    out[(size_t)(s * BATCH + j) * DIM + lane] = v;        // final_* accumulator (layer 0)
    out[(size_t)((s + 3) * BATCH + j) * DIM + lane] = v;  // init_* output
}

__global__ void gather_addscale(const float* __restrict__ e, const int* __restrict__ users,
                                const int* __restrict__ pos, const int* __restrict__ neg,
                                float* __restrict__ out, float scale) {
    const int t = blockIdx.x * blockDim.x + threadIdx.x;
    const int lane = t & 63;
    const int w = t >> 6;
    if (w >= 3 * BATCH) return;
    const int s = w / BATCH;
    const int j = w - s * BATCH;
    const int row = (s == 0) ? users[j] : (s == 1) ? pos[j] + N_USERS : neg[j] + N_USERS;
    const size_t o = (size_t)(s * BATCH + j) * DIM + lane;
    out[o] = (out[o] + e[(size_t)row * DIM + lane]) * scale;
}

// ---------------- host ----------------
extern "C" void kernel_launch(void* const* d_in, const int* in_sizes, int n_in,
                              void* d_out, int out_size, void* d_ws, size_t ws_size,
                              hipStream_t stream) {
    const float* emb  = (const float*)d_in[0];
    const int*   rows = (const int*)d_in[1];
    const int*   cols = (const int*)d_in[2];
    const float* vals = (const float*)d_in[3];
    const int*   users = (const int*)d_in[4];
    const int*   pos   = (const int*)d_in[5];
    const int*   neg   = (const int*)d_in[6];
    float* out = (float*)d_out;

    const int nE = in_sizes[1];
    auto rup = [](size_t x) { return (x + 255) & ~(size_t)255; };
    const size_t szBuf = rup((size_t)NTOT * DIM * sizeof(float));   // 64 MB
    const size_t szCol = rup((size_t)nE * sizeof(int));             // 16 MB
    const size_t szP   = rup((size_t)NTOT * sizeof(int));           // 1 MB
    const size_t szDis = rup((size_t)NTOT * sizeof(float));         // 1 MB
    const size_t szBk  = rup((size_t)(NB + 1) * sizeof(int));

    char* w = (char*)d_ws;
    float* bufA = (float*)w; w += szBuf;
    float* bufB = (float*)w; w += szBuf;
    int* entA   = (int*)bufB;              // phase-A entries alias bufB (dead before spmm-2)
    int*   ccol = (int*)w;   w += szCol;
    int*   P    = (int*)w;   w += szP;
    float* dis  = (float*)w; w += szDis;
    int* bCnt   = (int*)w;   w += szBk;
    int* bStart = (int*)w;   w += szBk;
    int* bCur   = (int*)w;   w += szBk;
    const size_t need = (size_t)((char*)w - (char*)d_ws);

    const int gatherBlocks = (3 * BATCH * DIM + 255) / 256;

    init_out<<<gatherBlocks, 256, 0, stream>>>(emb, users, pos, neg, out);

    if (ws_size >= need && nE > 0) {
        // ---- build bucketed CSR (coalesced two-phase counting sort) ----
        hipMemsetAsync(bCnt, 0, (size_t)NB * sizeof(int), stream);
        coarse_hist<<<512, 256, 0, stream>>>(rows, bCnt, nE);
        bucket_scan<<<1, 1024, 0, stream>>>(bCnt, bStart, bCur);
        const int nTiles = (nE + TILE - 1) / TILE;
        phase_a<<<nTiles, 256, 0, stream>>>(rows, cols, bCur, entA, nE);
        phase_b<<<NB, 256, 0, stream>>>(entA, bStart, ccol, P, dis);

        const int spmmBlocks = (NTOT + 3) / 4;
        // layers 1,2: full SpMM
        spmm_csr<<<spmmBlocks, 256, 0, stream>>>(emb,  P, ccol, dis, bufA);
        gather_addscale<<<gatherBlocks, 256, 0, stream>>>(bufA, users, pos, neg, out, 1.0f);
        spmm_csr<<<spmmBlocks, 256, 0, stream>>>(bufA, P, ccol, dis, bufB);
        gather_addscale<<<gatherBlocks, 256, 0, stream>>>(bufB, users, pos, neg, out, 1.0f);
        // layer 3: only sampled rows, fused accumulate + /4
        const int rowsBlocks = (3 * BATCH + 3) / 4;
        spmm_rows_out<<<rowsBlocks, 256, 0, stream>>>(bufB, P, ccol, dis, users, pos, neg, out);
    } else {
        // ---- atomic fallback ----
        const size_t bufBytes = (size_t)NTOT * DIM * sizeof(float);
        hipMemsetAsync(bufA, 0, bufBytes, stream);
        spmm_scatter<<<2048, 256, 0, stream>>>(emb, rows, cols, vals, bufA, nE);
        gather_addscale<<<gatherBlocks, 256, 0, stream>>>(bufA, users, pos, neg, out, 1.0f);
        hipMemsetAsync(bufB, 0, bufBytes, stream);
        spmm_scatter<<<2048, 256, 0, stream>>>(bufA, rows, cols, vals, bufB, nE);
        gather_addscale<<<gatherBlocks, 256, 0, stream>>>(bufB, users, pos, neg, out, 1.0f);
        hipMemsetAsync(bufA, 0, bufBytes, stream);
        spmm_scatter<<<2048, 256, 0, stream>>>(bufB, rows, cols, vals, bufA, nE);
        gather_addscale<<<gatherBlocks, 256, 0, stream>>>(bufA, users, pos, neg, out, 0.25f);
    }
}